// Round 16
// baseline (199.297 us; speedup 1.0000x reference)
//
#include <hip/hip_runtime.h>

typedef _Float16 h2 __attribute__((ext_vector_type(2)));
typedef _Float16 h4 __attribute__((ext_vector_type(4)));
typedef float f4 __attribute__((ext_vector_type(4)));

#define MAT_N 256
#define MAT_ELEMS (MAT_N * MAT_N)
// Convergence: absmax bit-identical (1.953e-3 = 2^-9 = f16 quantization
// floor) at 20/14/10/8/6 iterations (r10-r15); iterate cost is fully hidden
// under memory phases (r15: 6 iters == 8 iters within noise). Keep 8 for
// convergence margin at zero time cost.
#define NUM_ITERS 8
#define MPB 4   // matrices per persistent block; grid = 512 = exact residency

// ---- cross-lane DPP add (VALU pipe) --------------------------------------
template<int CTRL>
__device__ __forceinline__ float dpp_add(float x) {
    int i = __builtin_bit_cast(int, x);
    int r = __builtin_amdgcn_update_dpp(i, i, CTRL, 0xF, 0xF, true);
    return x + __builtin_bit_cast(float, r);
}
// Reduce across the 16 lanes sharing a row-group (DPP only). Proven r2-r15.
__device__ __forceinline__ float row16_reduce(float x) {
    x = dpp_add<0xB1>(x);    // quad_perm xor1
    x = dpp_add<0x4E>(x);    // quad_perm xor2
    x = dpp_add<0x141>(x);   // row_half_mirror (xor4)
    x = dpp_add<0x140>(x);   // row_mirror (xor8)
    return x;
}

__device__ __forceinline__ float dot2(h2 a, h2 b, float c) {
    return __builtin_amdgcn_fdot2(a, b, c, false);
}
// pack {f,f} -> h2 in one v_cvt_pkrtz_f16_f32 (proven r6-r15)
__device__ __forceinline__ h2 pkrtz(float a, float b) {
    return __builtin_bit_cast(h2, __builtin_amdgcn_cvt_pkrtz(a, b));
}
// NOTE: permlane16/32_swap builtins BANNED (r7/r8: identical wrong colsums).
// NOTE: per-row interleaved store+load epilogue BANNED (r11: qp pushed into
// AGPRs, VGPR_Count=72, -93 us). Phases stay strictly sequential with
// sched_barrier(0) between store and next-load.
// NOTE: s_sleep antiphase REMOVED this round (A/B vs r15): under the
// persistent structure, memory arbitration should self-desynchronize the two
// co-resident blocks; the deliberate 7us delay is then pure tail cost.

// 512-thread persistent block; 2 blocks/CU (empirical gfx950 rule:
// launch_bounds arg2=2 -> 128 arch-VGPR cap; live state ~105 -> no spill).
// Thread (R = tid>>4, C = tid&15) owns rows 8R..8R+7 and cols {4C..4C+3}+64d,
// d=0..3, f16-packed: qp[i][2d+m] = col-pair k = 2C+m+32d (cols 2k,2k+1).
__global__ __launch_bounds__(512, 2) void sinkhorn_kernel(
        const float* __restrict__ in, float* __restrict__ out) {
    const int tid = threadIdx.x;
    const int C = tid & 15;    // col-lane
    const int R = tid >> 4;    // row-group 0..31

    // Col partials as packed h2: Q1h[R][col-pair k], stride 130.
    __shared__ __align__(16) h2 Q1h[32][130];   // 16640 B
    __shared__ __align__(16) h2 Vch[128];       //   512 B packed col rcp

    const int m0 = blockIdx.x * MPB;

    // ---- initial load + exp -> f16 packed (64 VGPRs of state) ----
    h2 qp[8][8];
    {
        const f4* __restrict__ in4 = (const f4*)(in + (size_t)m0 * MAT_ELEMS);
        #pragma unroll
        for (int i = 0; i < 8; ++i) {
            #pragma unroll
            for (int d = 0; d < 4; ++d) {
                f4 t = in4[(8 * R + i) * 64 + C + 16 * d];
                h2 a, b;
                a.x = (_Float16)__expf(t.x); a.y = (_Float16)__expf(t.y);
                b.x = (_Float16)__expf(t.z); b.y = (_Float16)__expf(t.w);
                qp[i][2 * d] = a; qp[i][2 * d + 1] = b;
            }
        }
    }

    #pragma unroll 1
    for (int mi = 0; mi < MPB; ++mi) {
        h2 vp[8];
        {
            h2 one; one.x = (_Float16)1.f; one.y = (_Float16)1.f;
            #pragma unroll
            for (int j = 0; j < 8; ++j) vp[j] = one;
        }
        float u[8];

        // ================= iterate (identical core to r10-r15) =============
        #pragma unroll 1
        for (int it = 0; it < NUM_ITERS; ++it) {
            // ---- row phase: u = 1/(M v). dot2 + pure-DPP 16-lane reduce ----
            #pragma unroll
            for (int i = 0; i < 8; ++i) {
                float s = dot2(qp[i][0], vp[0], 0.f);
                #pragma unroll
                for (int jj = 1; jj < 8; ++jj) s = dot2(qp[i][jj], vp[jj], s);
                s = row16_reduce(s);
                u[i] = __builtin_amdgcn_rcpf(s);
            }

            // ---- col phase: packed-f16 accumulation ----
            h2 ca[8];
            {
                h2 z; z.x = (_Float16)0.f; z.y = (_Float16)0.f;
                #pragma unroll
                for (int p = 0; p < 8; ++p) ca[p] = z;
            }
            #pragma unroll
            for (int i = 0; i < 8; ++i) {
                const h2 ub = pkrtz(u[i], u[i]);
                #pragma unroll
                for (int p = 0; p < 8; ++p)
                    ca[p] = __builtin_elementwise_fma(qp[i][p], ub, ca[p]);
            }

            // write packed partials: 4x ds_write_b64
            #pragma unroll
            for (int d = 0; d < 4; ++d) {
                h4 wv;
                wv.x = ca[2 * d].x;     wv.y = ca[2 * d].y;
                wv.z = ca[2 * d + 1].x; wv.w = ca[2 * d + 1].y;
                *(h4*)&Q1h[R][2 * C + 32 * d] = wv;
            }
            __syncthreads();

            {   // stage 2: col-pair cp; quad sums 8 of 32 R-rows
                const int cp = tid >> 2;
                const int r0 = (tid & 3) * 8;
                h2 p0 = Q1h[r0 + 0][cp] + Q1h[r0 + 1][cp];
                h2 p1 = Q1h[r0 + 2][cp] + Q1h[r0 + 3][cp];
                h2 p2 = Q1h[r0 + 4][cp] + Q1h[r0 + 5][cp];
                h2 p3 = Q1h[r0 + 6][cp] + Q1h[r0 + 7][cp];
                float lo = ((float)p0.x + (float)p1.x) + ((float)p2.x + (float)p3.x);
                float hi = ((float)p0.y + (float)p1.y) + ((float)p2.y + (float)p3.y);
                lo = dpp_add<0xB1>(lo); lo = dpp_add<0x4E>(lo);
                hi = dpp_add<0xB1>(hi); hi = dpp_add<0x4E>(hi);
                if ((tid & 3) == 0) {
                    Vch[cp] = pkrtz(__builtin_amdgcn_rcpf(lo),
                                    __builtin_amdgcn_rcpf(hi));
                }
            }
            __syncthreads();

            // ---- reload v: 4x b64 broadcast reads, no cvt ----
            #pragma unroll
            for (int d = 0; d < 4; ++d) {
                h4 t = *(const h4*)&Vch[2 * C + 32 * d];
                h2 t0, t1;
                t0.x = t.x; t0.y = t.y; t1.x = t.z; t1.y = t.w;
                vp[2 * d] = t0; vp[2 * d + 1] = t1;
            }
        }

        // ===== store matrix mi (nontemporal; drains under next load/iterate)
        {
            f4* __restrict__ out4 = (f4*)(out + (size_t)(m0 + mi) * MAT_ELEMS);
            float vf[16];
            #pragma unroll
            for (int p = 0; p < 8; ++p) {
                vf[2 * p]     = (float)vp[p].x;
                vf[2 * p + 1] = (float)vp[p].y;
            }
            #pragma unroll
            for (int i = 0; i < 8; ++i) {
                const float s = u[i];
                #pragma unroll
                for (int d = 0; d < 4; ++d) {
                    f4 o;
                    o.x = (float)qp[i][2 * d].x     * (s * vf[4 * d]);
                    o.y = (float)qp[i][2 * d].y     * (s * vf[4 * d + 1]);
                    o.z = (float)qp[i][2 * d + 1].x * (s * vf[4 * d + 2]);
                    o.w = (float)qp[i][2 * d + 1].y * (s * vf[4 * d + 3]);
                    __builtin_nontemporal_store(o, &out4[(8 * R + i) * 64 + C + 16 * d]);
                }
            }
        }

        // ===== load matrix mi+1 (phase-separated: no hoisting into stores) ==
        if (mi + 1 < MPB) {
            __builtin_amdgcn_sched_barrier(0);
            const f4* __restrict__ nin4 =
                (const f4*)(in + (size_t)(m0 + mi + 1) * MAT_ELEMS);
            #pragma unroll
            for (int i = 0; i < 8; ++i) {
                #pragma unroll
                for (int d = 0; d < 4; ++d) {
                    f4 t = nin4[(8 * R + i) * 64 + C + 16 * d];
                    h2 a, b;
                    a.x = (_Float16)__expf(t.x); a.y = (_Float16)__expf(t.y);
                    b.x = (_Float16)__expf(t.z); b.y = (_Float16)__expf(t.w);
                    qp[i][2 * d] = a; qp[i][2 * d + 1] = b;
                }
            }
        }
    }
}

extern "C" void kernel_launch(void* const* d_in, const int* in_sizes, int n_in,
                              void* d_out, int out_size, void* d_ws, size_t ws_size,
                              hipStream_t stream) {
    const float* in = (const float*)d_in[0];
    float* out = (float*)d_out;
    const int nmat = in_sizes[0] / MAT_ELEMS;   // 2048
    const int grid = nmat / MPB;                // 512: all blocks resident
    sinkhorn_kernel<<<grid, 512, 0, stream>>>(in, out);
}

// Round 17
// 195.715 us; speedup vs baseline: 1.0183x; 1.0183x over previous
//
#include <hip/hip_runtime.h>

typedef _Float16 h2 __attribute__((ext_vector_type(2)));
typedef _Float16 h4 __attribute__((ext_vector_type(4)));
typedef float f4 __attribute__((ext_vector_type(4)));

#define MAT_N 256
#define MAT_ELEMS (MAT_N * MAT_N)
// Convergence: absmax bit-identical (1.953e-3 = 2^-9 = f16 quantization
// floor) at 20/14/10/8/6 iterations (r10-r15); iterate cost fully hidden
// under memory phases. Keep 8 for convergence margin at zero time cost.
#define NUM_ITERS 8
#define MPB 4   // matrices per persistent block; grid = 512 = exact residency

// ---- cross-lane DPP add (VALU pipe) --------------------------------------
template<int CTRL>
__device__ __forceinline__ float dpp_add(float x) {
    int i = __builtin_bit_cast(int, x);
    int r = __builtin_amdgcn_update_dpp(i, i, CTRL, 0xF, 0xF, true);
    return x + __builtin_bit_cast(float, r);
}
// Reduce across the 16 lanes sharing a row-group (DPP only). Proven r2-r16.
__device__ __forceinline__ float row16_reduce(float x) {
    x = dpp_add<0xB1>(x);    // quad_perm xor1
    x = dpp_add<0x4E>(x);    // quad_perm xor2
    x = dpp_add<0x141>(x);   // row_half_mirror (xor4)
    x = dpp_add<0x140>(x);   // row_mirror (xor8)
    return x;
}

__device__ __forceinline__ float dot2(h2 a, h2 b, float c) {
    return __builtin_amdgcn_fdot2(a, b, c, false);
}
// pack {f,f} -> h2 in one v_cvt_pkrtz_f16_f32 (proven r6-r16)
__device__ __forceinline__ h2 pkrtz(float a, float b) {
    return __builtin_bit_cast(h2, __builtin_amdgcn_cvt_pkrtz(a, b));
}
// NOTE: permlane16/32_swap builtins BANNED (r7/r8: identical wrong colsums).
// NOTE: per-row interleaved store+load epilogue BANNED (r11: qp pushed into
// AGPRs, VGPR_Count=72, -93 us). Phases stay strictly sequential with
// sched_barrier(0) between store and next-load.
// ANTIPHASE FIX (r17): with grid=512, round-robin XCD dispatch + sequential
// CU fill means co-resident pairs are (b, b+256) — parity is (bid>>8)&1.
// r10-r15 used (bid>>3)&1, which is IDENTICAL for b and b+256: both-or-
// neither siblings slept (pure tail cost, no antiphase). Offset ~10us
// (> ~7.4us compute phase) keeps the CU memory pipe continuously busy.

// 512-thread persistent block; 2 blocks/CU (empirical gfx950 rule:
// launch_bounds arg2=2 -> 128 arch-VGPR cap; live state ~105 -> no spill).
// Thread (R = tid>>4, C = tid&15) owns rows 8R..8R+7 and cols {4C..4C+3}+64d,
// d=0..3, f16-packed: qp[i][2d+m] = col-pair k = 2C+m+32d (cols 2k,2k+1).
__global__ __launch_bounds__(512, 2) void sinkhorn_kernel(
        const float* __restrict__ in, float* __restrict__ out) {
    const int tid = threadIdx.x;
    const int C = tid & 15;    // col-lane
    const int R = tid >> 4;    // row-group 0..31

    // Col partials as packed h2: Q1h[R][col-pair k], stride 130.
    __shared__ __align__(16) h2 Q1h[32][130];   // 16640 B
    __shared__ __align__(16) h2 Vch[128];       //   512 B packed col rcp

    // ---- antiphase: delay the SECOND co-resident block (b+256) ~10us ----
    if ((blockIdx.x >> 8) & 1) {
        __builtin_amdgcn_s_sleep(127);
        __builtin_amdgcn_s_sleep(127);
        __builtin_amdgcn_s_sleep(127);
    }

    const int m0 = blockIdx.x * MPB;

    // ---- initial load + exp -> f16 packed (64 VGPRs of state) ----
    h2 qp[8][8];
    {
        const f4* __restrict__ in4 = (const f4*)(in + (size_t)m0 * MAT_ELEMS);
        #pragma unroll
        for (int i = 0; i < 8; ++i) {
            #pragma unroll
            for (int d = 0; d < 4; ++d) {
                f4 t = in4[(8 * R + i) * 64 + C + 16 * d];
                h2 a, b;
                a.x = (_Float16)__expf(t.x); a.y = (_Float16)__expf(t.y);
                b.x = (_Float16)__expf(t.z); b.y = (_Float16)__expf(t.w);
                qp[i][2 * d] = a; qp[i][2 * d + 1] = b;
            }
        }
    }

    #pragma unroll 1
    for (int mi = 0; mi < MPB; ++mi) {
        h2 vp[8];
        {
            h2 one; one.x = (_Float16)1.f; one.y = (_Float16)1.f;
            #pragma unroll
            for (int j = 0; j < 8; ++j) vp[j] = one;
        }
        float u[8];

        // ================= iterate (identical core to r10-r16) =============
        #pragma unroll 1
        for (int it = 0; it < NUM_ITERS; ++it) {
            // ---- row phase: u = 1/(M v). dot2 + pure-DPP 16-lane reduce ----
            #pragma unroll
            for (int i = 0; i < 8; ++i) {
                float s = dot2(qp[i][0], vp[0], 0.f);
                #pragma unroll
                for (int jj = 1; jj < 8; ++jj) s = dot2(qp[i][jj], vp[jj], s);
                s = row16_reduce(s);
                u[i] = __builtin_amdgcn_rcpf(s);
            }

            // ---- col phase: packed-f16 accumulation ----
            h2 ca[8];
            {
                h2 z; z.x = (_Float16)0.f; z.y = (_Float16)0.f;
                #pragma unroll
                for (int p = 0; p < 8; ++p) ca[p] = z;
            }
            #pragma unroll
            for (int i = 0; i < 8; ++i) {
                const h2 ub = pkrtz(u[i], u[i]);
                #pragma unroll
                for (int p = 0; p < 8; ++p)
                    ca[p] = __builtin_elementwise_fma(qp[i][p], ub, ca[p]);
            }

            // write packed partials: 4x ds_write_b64
            #pragma unroll
            for (int d = 0; d < 4; ++d) {
                h4 wv;
                wv.x = ca[2 * d].x;     wv.y = ca[2 * d].y;
                wv.z = ca[2 * d + 1].x; wv.w = ca[2 * d + 1].y;
                *(h4*)&Q1h[R][2 * C + 32 * d] = wv;
            }
            __syncthreads();

            {   // stage 2: col-pair cp; quad sums 8 of 32 R-rows
                const int cp = tid >> 2;
                const int r0 = (tid & 3) * 8;
                h2 p0 = Q1h[r0 + 0][cp] + Q1h[r0 + 1][cp];
                h2 p1 = Q1h[r0 + 2][cp] + Q1h[r0 + 3][cp];
                h2 p2 = Q1h[r0 + 4][cp] + Q1h[r0 + 5][cp];
                h2 p3 = Q1h[r0 + 6][cp] + Q1h[r0 + 7][cp];
                float lo = ((float)p0.x + (float)p1.x) + ((float)p2.x + (float)p3.x);
                float hi = ((float)p0.y + (float)p1.y) + ((float)p2.y + (float)p3.y);
                lo = dpp_add<0xB1>(lo); lo = dpp_add<0x4E>(lo);
                hi = dpp_add<0xB1>(hi); hi = dpp_add<0x4E>(hi);
                if ((tid & 3) == 0) {
                    Vch[cp] = pkrtz(__builtin_amdgcn_rcpf(lo),
                                    __builtin_amdgcn_rcpf(hi));
                }
            }
            __syncthreads();

            // ---- reload v: 4x b64 broadcast reads, no cvt ----
            #pragma unroll
            for (int d = 0; d < 4; ++d) {
                h4 t = *(const h4*)&Vch[2 * C + 32 * d];
                h2 t0, t1;
                t0.x = t.x; t0.y = t.y; t1.x = t.z; t1.y = t.w;
                vp[2 * d] = t0; vp[2 * d + 1] = t1;
            }
        }

        // ===== store matrix mi (nontemporal; drains under next load/iterate)
        {
            f4* __restrict__ out4 = (f4*)(out + (size_t)(m0 + mi) * MAT_ELEMS);
            float vf[16];
            #pragma unroll
            for (int p = 0; p < 8; ++p) {
                vf[2 * p]     = (float)vp[p].x;
                vf[2 * p + 1] = (float)vp[p].y;
            }
            #pragma unroll
            for (int i = 0; i < 8; ++i) {
                const float s = u[i];
                #pragma unroll
                for (int d = 0; d < 4; ++d) {
                    f4 o;
                    o.x = (float)qp[i][2 * d].x     * (s * vf[4 * d]);
                    o.y = (float)qp[i][2 * d].y     * (s * vf[4 * d + 1]);
                    o.z = (float)qp[i][2 * d + 1].x * (s * vf[4 * d + 2]);
                    o.w = (float)qp[i][2 * d + 1].y * (s * vf[4 * d + 3]);
                    __builtin_nontemporal_store(o, &out4[(8 * R + i) * 64 + C + 16 * d]);
                }
            }
        }

        // ===== load matrix mi+1 (phase-separated: no hoisting into stores) ==
        if (mi + 1 < MPB) {
            __builtin_amdgcn_sched_barrier(0);
            const f4* __restrict__ nin4 =
                (const f4*)(in + (size_t)(m0 + mi + 1) * MAT_ELEMS);
            #pragma unroll
            for (int i = 0; i < 8; ++i) {
                #pragma unroll
                for (int d = 0; d < 4; ++d) {
                    f4 t = nin4[(8 * R + i) * 64 + C + 16 * d];
                    h2 a, b;
                    a.x = (_Float16)__expf(t.x); a.y = (_Float16)__expf(t.y);
                    b.x = (_Float16)__expf(t.z); b.y = (_Float16)__expf(t.w);
                    qp[i][2 * d] = a; qp[i][2 * d + 1] = b;
                }
            }
        }
    }
}

extern "C" void kernel_launch(void* const* d_in, const int* in_sizes, int n_in,
                              void* d_out, int out_size, void* d_ws, size_t ws_size,
                              hipStream_t stream) {
    const float* in = (const float*)d_in[0];
    float* out = (float*)d_out;
    const int nmat = in_sizes[0] / MAT_ELEMS;   // 2048
    const int grid = nmat / MPB;                // 512: all blocks resident
    sinkhorn_kernel<<<grid, 512, 0, stream>>>(in, out);
}